// Round 14
// baseline (135.512 us; speedup 1.0000x reference)
//
#include <hip/hip_runtime.h>

#define DFEAT 64
#define BKSZ 512            // nodes per bucket (CSR build)
#define SB 9                // log2(BKSZ)
#define NBKT_PAD 256        // max buckets; nbkt <= 256
#define PLACE_CHUNK 4096
#define CAP 12288           // fixed slots per bucket in pairs (mean 8192)
#define FILL_CAP 12288      // LDS pair cache per bucket (48KB)

typedef __attribute__((ext_vector_type(8))) short bf16x8;
typedef __attribute__((ext_vector_type(4))) float f32x4;

__device__ inline unsigned short f2bf(float f) {
  unsigned int x = __float_as_uint(f);
  return (unsigned short)((x + 0x7fffu + ((x >> 16) & 1u)) >> 16);
}

// ===========================================================================
// K1: fused bf16 conversion (feat + sentinel row + W) AND bucket place.
// Fixed-stride bucket regions; no histogram, no global scan.  Rare overflow
// spills to ov[]; fillk merges it (free when empty).
// ===========================================================================
__global__ __launch_bounds__(512) void gcn_place_conv(
    const float4* __restrict__ feat4, ushort4* __restrict__ gb4, int n4,
    const float4* __restrict__ w4, ushort4* __restrict__ wb4, int nw4,
    const int* __restrict__ src, const int* __restrict__ dst,
    int* __restrict__ bcur, int* __restrict__ ocnt,
    unsigned int* __restrict__ pairs, int2* __restrict__ ov,
    int n_edges, int nbkt) {
  int total = n4 + 16 + nw4;
  for (int i = blockIdx.x * 512 + threadIdx.x; i < total; i += gridDim.x * 512) {
    if (i < n4) {
      float4 f = feat4[i];
      ushort4 u;
      u.x = f2bf(f.x); u.y = f2bf(f.y); u.z = f2bf(f.z); u.w = f2bf(f.w);
      gb4[i] = u;
    } else if (i < n4 + 16) {
      gb4[i] = (ushort4){0, 0, 0, 0};          // sentinel row (node n_nodes)
    } else {
      float4 f = w4[i - n4 - 16];
      ushort4 u;
      u.x = f2bf(f.x); u.y = f2bf(f.y); u.z = f2bf(f.z); u.w = f2bf(f.w);
      wb4[i - n4 - 16] = u;
    }
  }

  __shared__ int cnt[NBKT_PAD];                    // 1 KB
  __shared__ int base[NBKT_PAD];                   // 1 KB
  __shared__ unsigned int pk[PLACE_CHUNK];         // 16 KB
  __shared__ unsigned char bk[PLACE_CHUNK];        // 4 KB
  int t = threadIdx.x;
  if (t < NBKT_PAD) cnt[t] = 0;
  __syncthreads();

  int e0 = blockIdx.x * PLACE_CHUNK;
  int e1 = min(e0 + PLACE_CHUNK, n_edges);
  for (int e = e0 + t; e < e1; e += 512) {
    int d = dst[e];
    int s = src[e];
    int b = d >> SB;
    pk[e - e0] = (unsigned)s | ((unsigned)(d & (BKSZ - 1)) << 23);
    bk[e - e0] = (unsigned char)b;
    atomicAdd(&cnt[b], 1);
  }
  __syncthreads();
  if (t < NBKT_PAD) {
    int c = cnt[t];
    base[t] = c ? atomicAdd(&bcur[t], c) : 0;   // bucket-relative reservation
    cnt[t] = 0;   // reuse as local cursor
  }
  __syncthreads();
  for (int e = e0 + t; e < e1; e += 512) {
    int b = bk[e - e0];
    int rel = base[b] + atomicAdd(&cnt[b], 1);
    unsigned p = pk[e - e0];
    if (rel < CAP) {
      pairs[b * CAP + rel] = p;
    } else {                                    // adversarial only
      int oi = atomicAdd(ocnt, 1);
      ov[oi] = make_int2((int)(p & 0x7FFFFFu), (b << 9) | (int)(p >> 23));
    }
  }
}

// ===========================================================================
// K2: per-bucket fill.  Bucket totals = min(bcur,CAP) + overflow count;
// cheap local scan -> compact CSR base; node-degree hist -> scan -> offsets
// + cursor placement of edge_src.  Overflow merged (free when empty).
// ===========================================================================
__global__ __launch_bounds__(512) void gcn_fillk(
    const unsigned int* __restrict__ pairs, const int2* __restrict__ ov,
    const int* __restrict__ ocnt_p, const int* __restrict__ bcur,
    int* __restrict__ offsets, int* __restrict__ edge_src,
    int n_nodes, int n_edges, int nbkt) {
  __shared__ int sc[2][NBKT_PAD];       // 2 KB
  __shared__ int ovb[NBKT_PAD];         // 1 KB
  __shared__ int deg[BKSZ];             // 2 KB
  __shared__ int buf[2][BKSZ];          // 4 KB
  __shared__ int cur[BKSZ];             // 2 KB
  __shared__ unsigned int lp[FILL_CAP]; // 48 KB
  int b = blockIdx.x, t = threadIdx.x;
  int onum = ocnt_p[0];

  if (t < NBKT_PAD) ovb[t] = 0;
  __syncthreads();
  for (int i = t; i < onum; i += 512) atomicAdd(&ovb[ov[i].y >> 9], 1);
  __syncthreads();

  if (t < NBKT_PAD)
    sc[0][t] = (t < nbkt) ? (min(bcur[t], CAP) + ovb[t]) : 0;
  __syncthreads();
  int pin = 0;
  for (int s = 1; s < NBKT_PAD; s <<= 1) {
    int po = pin ^ 1;
    if (t < NBKT_PAD) {
      int v = sc[pin][t];
      if (t >= s) v += sc[pin][t - s];
      sc[po][t] = v;
    }
    __syncthreads();
    pin = po;
  }
  int e0 = (b == 0) ? 0 : sc[pin][b - 1];
  int mc = min(bcur[b], CAP);
  int n0 = b << SB;
  bool fits = (mc <= FILL_CAP);

  deg[t] = 0;
  __syncthreads();
  if (fits) {
    for (int i = t; i < mc; i += 512) {
      unsigned p = pairs[b * CAP + i];
      lp[i] = p;
      atomicAdd(&deg[p >> 23], 1);
    }
  } else {
    for (int i = t; i < mc; i += 512)
      atomicAdd(&deg[pairs[b * CAP + i] >> 23], 1);
  }
  for (int i = t; i < onum; i += 512) {
    int2 o = ov[i];
    if ((o.y >> 9) == b) atomicAdd(&deg[o.y & (BKSZ - 1)], 1);
  }
  __syncthreads();
  buf[0][t] = deg[t];
  __syncthreads();
  pin = 0;
  for (int s = 1; s < BKSZ; s <<= 1) {
    int po = pin ^ 1;
    int v = buf[pin][t];
    if (t >= s) v += buf[pin][t - s];
    buf[po][t] = v;
    __syncthreads();
    pin = po;
  }
  int excl = (t == 0) ? 0 : buf[pin][t - 1];
  cur[t] = excl;
  int n = n0 + t;
  if (n < n_nodes) offsets[n] = e0 + excl;
  if (b == nbkt - 1 && t == 0) offsets[n_nodes] = n_edges;
  __syncthreads();
  if (fits) {
    for (int i = t; i < mc; i += 512) {
      unsigned p = lp[i];
      int pos = atomicAdd(&cur[p >> 23], 1);
      edge_src[e0 + pos] = (int)(p & 0x7FFFFFu);
    }
  } else {
    for (int i = t; i < mc; i += 512) {
      unsigned p = pairs[b * CAP + i];
      int pos = atomicAdd(&cur[p >> 23], 1);
      edge_src[e0 + pos] = (int)(p & 0x7FFFFFu);
    }
  }
  for (int i = t; i < onum; i += 512) {
    int2 o = ov[i];
    if ((o.y >> 9) == b) {
      int pos = atomicAdd(&cur[o.y & (BKSZ - 1)], 1);
      edge_src[e0 + pos] = o.x;
    }
  }
}

// ===========================================================================
// K3: fused gather + concat + MFMA Linear.
// Block = 128 thr = 2 waves; each wave owns 16 nodes, no barriers.
//
// NEW: nodes processed in PAIRS (r, r+1) with separate accumulator sets and
// interleaved gather loads -> 8 independent 128B loads in flight per wave
// (was 4); prefetch covers the next pair.  MLP x latency was the gather
// ceiling (~4 TB/s cache throughput at 4 loads deep).
// ===========================================================================
__global__ __launch_bounds__(128, 6) void gcn_gather_mfma(
    const ushort4* __restrict__ gb4,         // [N+1][16] bf16, row N = zeros
    const unsigned short* __restrict__ wb,   // [64][128] bf16 W
    const int* __restrict__ edge_src,
    const int* __restrict__ offsets,
    const float* __restrict__ bias,          // [64]
    float* __restrict__ out,                 // [N][64]
    int n_nodes) {
  __shared__ unsigned short hl[2][16 * 64];   // 4 KB total (agg half only)
  int tid = threadIdx.x;
  int wave = tid >> 6, lane = tid & 63;
  int q = lane >> 4, kk = lane & 15;
  int lrow = lane & 15, lkg = lane >> 4;
  unsigned short* myhl = hl[wave];
  int node0 = blockIdx.x * 32 + wave * 16;
  const int SENT = n_nodes;

  // ---- one-shot offsets batch for this wave's 16 nodes ----
  int oidx = node0 + ((lane < 16) ? lane : 16);
  if (oidx > n_nodes) oidx = n_nodes;
  int offv = offsets[oidx];
  int nvalid = n_nodes - node0;
  if (nvalid > 16) nvalid = 16;

  auto proc16 = [&](int idreg, int j, float4& a0, float4& a1, float4& a2,
                    float4& a3) {
    int s0 = __shfl(idreg, j + q);
    int s1 = __shfl(idreg, j + 4 + q);
    int s2 = __shfl(idreg, j + 8 + q);
    int s3 = __shfl(idreg, j + 12 + q);
    uint2 w0 = *(const uint2*)&gb4[s0 * 16 + kk];
    uint2 w1 = *(const uint2*)&gb4[s1 * 16 + kk];
    uint2 w2 = *(const uint2*)&gb4[s2 * 16 + kk];
    uint2 w3 = *(const uint2*)&gb4[s3 * 16 + kk];
    a0.x += __uint_as_float(w0.x << 16);
    a0.y += __uint_as_float(w0.x & 0xffff0000u);
    a0.z += __uint_as_float(w0.y << 16);
    a0.w += __uint_as_float(w0.y & 0xffff0000u);
    a1.x += __uint_as_float(w1.x << 16);
    a1.y += __uint_as_float(w1.x & 0xffff0000u);
    a1.z += __uint_as_float(w1.y << 16);
    a1.w += __uint_as_float(w1.y & 0xffff0000u);
    a2.x += __uint_as_float(w2.x << 16);
    a2.y += __uint_as_float(w2.x & 0xffff0000u);
    a2.z += __uint_as_float(w2.y << 16);
    a2.w += __uint_as_float(w2.y & 0xffff0000u);
    a3.x += __uint_as_float(w3.x << 16);
    a3.y += __uint_as_float(w3.x & 0xffff0000u);
    a3.z += __uint_as_float(w3.y << 16);
    a3.w += __uint_as_float(w3.y & 0xffff0000u);
  };

  auto reduce_store = [&](int r, float4 a0, float4 a1, float4 a2, float4 a3) {
    float4 acc;
    acc.x = (a0.x + a1.x) + (a2.x + a3.x);
    acc.y = (a0.y + a1.y) + (a2.y + a3.y);
    acc.z = (a0.z + a1.z) + (a2.z + a3.z);
    acc.w = (a0.w + a1.w) + (a2.w + a3.w);
    acc.x += __shfl_xor(acc.x, 16); acc.x += __shfl_xor(acc.x, 32);
    acc.y += __shfl_xor(acc.y, 16); acc.y += __shfl_xor(acc.y, 32);
    acc.z += __shfl_xor(acc.z, 16); acc.z += __shfl_xor(acc.z, 32);
    acc.w += __shfl_xor(acc.w, 16); acc.w += __shfl_xor(acc.w, 32);
    if (q == 0) {                 // agg fragment: 8B per lane, swizzled
      unsigned swz = (unsigned)((r & 7) << 4);
      char* rowp = (char*)(myhl + r * 64);
      ushort4 pk;
      pk.x = f2bf(acc.x); pk.y = f2bf(acc.y);
      pk.z = f2bf(acc.z); pk.w = f2bf(acc.w);
      *(ushort4*)(rowp + ((8u * (unsigned)kk) ^ swz)) = pk;
    }
  };

  // ---- prefetch first pair's id batches ----
  int idv1 = SENT, idv2 = SENT;
  if (nvalid > 0) {
    int o = __shfl(offv, 0);
    int d = __shfl(offv, 1) - o;
    if (lane < d) idv1 = edge_src[o + lane];
  }
  if (nvalid > 1) {
    int o = __shfl(offv, 1);
    int d = __shfl(offv, 2) - o;
    if (lane < d) idv2 = edge_src[o + lane];
  }

  for (int r = 0; r < nvalid; r += 2) {
    int off1 = __shfl(offv, r);
    int deg1 = __shfl(offv, r + 1) - off1;
    int off2 = 0, deg2 = 0;
    if (r + 1 < nvalid) {
      off2 = __shfl(offv, r + 1);
      deg2 = __shfl(offv, r + 2) - off2;
    }

    // prefetch next pair's first id batches (overlap with this pair's work)
    int idn1 = SENT, idn2 = SENT;
    if (r + 2 < nvalid) {
      int o = __shfl(offv, r + 2);
      int d = __shfl(offv, r + 3) - o;
      if (lane < d) idn1 = edge_src[o + lane];
    }
    if (r + 3 < nvalid) {
      int o = __shfl(offv, r + 3);
      int d = __shfl(offv, r + 4) - o;
      if (lane < d) idn2 = edge_src[o + lane];
    }

    float4 a0 = {0.f, 0.f, 0.f, 0.f}, a1 = a0, a2 = a0, a3 = a0;
    float4 b0 = a0, b1 = a0, b2 = a0, b3 = a0;
    int lim1 = min(deg1, 64), lim2 = min(deg2, 64);
    int limm = max(lim1, lim2);
    for (int j = 0; j < limm; j += 16) {
      if (j < lim1) proc16(idv1, j, a0, a1, a2, a3);
      if (j < lim2) proc16(idv2, j, b0, b1, b2, b3);
    }
    for (int base = 64; base < deg1; base += 64) {          // rare overflow
      int id2 = (base + lane < deg1) ? edge_src[off1 + base + lane] : SENT;
      int lm = min(64, deg1 - base);
      for (int j = 0; j < lm; j += 16) proc16(id2, j, a0, a1, a2, a3);
    }
    for (int base = 64; base < deg2; base += 64) {
      int id2 = (base + lane < deg2) ? edge_src[off2 + base + lane] : SENT;
      int lm = min(64, deg2 - base);
      for (int j = 0; j < lm; j += 16) proc16(id2, j, b0, b1, b2, b3);
    }

    reduce_store(r, a0, a1, a2, a3);
    if (r + 1 < nvalid) reduce_store(r + 1, b0, b1, b2, b3);
    idv1 = idn1;
    idv2 = idn2;
  }

  // ---- W B-frags into registers ----
  bf16x8 wf[4][4];
#pragma unroll
  for (int kt = 0; kt < 4; ++kt)
#pragma unroll
    for (int jt = 0; jt < 4; ++jt)
      wf[kt][jt] =
          *(const bf16x8*)(wb + (jt * 16 + lrow) * 128 + kt * 32 + lkg * 8);

  f32x4 acc[4];
#pragma unroll
  for (int jt = 0; jt < 4; ++jt) acc[jt] = (f32x4){0.f, 0.f, 0.f, 0.f};

  // feat half (k 0..63): straight from global bf16 table
  int nrow = node0 + lrow;
  int nload = (nrow < n_nodes) ? nrow : n_nodes;   // sentinel row if OOB
#pragma unroll
  for (int kt = 0; kt < 2; ++kt) {
    bf16x8 af = *(const bf16x8*)((const unsigned short*)gb4 +
                                 (size_t)nload * DFEAT + kt * 32 + lkg * 8);
#pragma unroll
    for (int jt = 0; jt < 4; ++jt)
      acc[jt] = __builtin_amdgcn_mfma_f32_16x16x32_bf16(af, wf[kt][jt],
                                                        acc[jt], 0, 0, 0);
  }
  // agg half (k 64..127): from wave-private LDS (swizzled)
  unsigned aswz = (unsigned)((lrow & 7) << 4);
  const char* arow = (const char*)(myhl + lrow * 64);
#pragma unroll
  for (int kt = 2; kt < 4; ++kt) {
    bf16x8 af =
        *(const bf16x8*)(arow + ((unsigned)((kt - 2) * 64 + lkg * 16) ^ aswz));
#pragma unroll
    for (int jt = 0; jt < 4; ++jt)
      acc[jt] = __builtin_amdgcn_mfma_f32_16x16x32_bf16(af, wf[kt][jt],
                                                        acc[jt], 0, 0, 0);
  }

#pragma unroll
  for (int jt = 0; jt < 4; ++jt) {
    float bj = bias[jt * 16 + lrow];
#pragma unroll
    for (int r = 0; r < 4; ++r) {
      int n = node0 + lkg * 4 + r;
      if (n < n_nodes) out[n * DFEAT + jt * 16 + lrow] = acc[jt][r] + bj;
    }
  }
}

// ===========================================================================
// Last-resort fallback: atomic scatter + separate vector GEMM.
// ===========================================================================
__global__ __launch_bounds__(256) void gcn_scatter_kernel(
    const float4* __restrict__ feat4, const int* __restrict__ src,
    const int* __restrict__ dst, float* __restrict__ agg, int n_edges) {
  long long gid = (long long)blockIdx.x * blockDim.x + threadIdx.x;
  int e = (int)(gid >> 4);
  int c = (int)(gid & 15);
  if (e >= n_edges) return;
  float4 v = feat4[src[e] * 16 + c];
  float* p = agg + dst[e] * DFEAT + c * 4;
  atomicAdd(p + 0, v.x);
  atomicAdd(p + 1, v.y);
  atomicAdd(p + 2, v.z);
  atomicAdd(p + 3, v.w);
}

__global__ __launch_bounds__(256) void gcn_gemm_kernel(
    const float* __restrict__ feat, const float* __restrict__ agg,
    const float* __restrict__ W, const float* __restrict__ bias,
    float* __restrict__ out, int n_nodes) {
  __shared__ float4 Wl4[2048];
  __shared__ __align__(16) float hlf[16][128];
  int tid = threadIdx.x;
  for (int i = tid; i < 2048; i += 256) {
    int j = i >> 5, k4 = i & 31;
    Wl4[k4 * 64 + (j ^ (k4 & 7))] = ((const float4*)W)[i];
  }
  int node0 = blockIdx.x * 16;
  int wave = tid >> 6, lane = tid & 63;
  int mbase = wave * 4;
#pragma unroll
  for (int r = 0; r < 4; ++r) {
    int n = node0 + mbase + r;
    if (n < n_nodes) {
      hlf[mbase + r][lane]      = feat[n * DFEAT + lane];
      hlf[mbase + r][64 + lane] = agg[n * DFEAT + lane];
    }
  }
  __syncthreads();
  float a0 = 0.f, a1 = 0.f, a2 = 0.f, a3 = 0.f;
#pragma unroll 4
  for (int k4 = 0; k4 < 32; ++k4) {
    float4 w  = Wl4[k4 * 64 + (lane ^ (k4 & 7))];
    float4 h0 = *((const float4*)&hlf[mbase + 0][k4 * 4]);
    float4 h1 = *((const float4*)&hlf[mbase + 1][k4 * 4]);
    float4 h2 = *((const float4*)&hlf[mbase + 2][k4 * 4]);
    float4 h3 = *((const float4*)&hlf[mbase + 3][k4 * 4]);
    a0 += w.x * h0.x + w.y * h0.y + w.z * h0.z + w.w * h0.w;
    a1 += w.x * h1.x + w.y * h1.y + w.z * h1.z + w.w * h1.w;
    a2 += w.x * h2.x + w.y * h2.y + w.z * h2.z + w.w * h2.w;
    a3 += w.x * h3.x + w.y * h3.y + w.z * h3.z + w.w * h3.w;
  }
  float bj = bias[lane];
  int n = node0 + mbase;
  if (n + 0 < n_nodes) out[(n + 0) * DFEAT + lane] = a0 + bj;
  if (n + 1 < n_nodes) out[(n + 1) * DFEAT + lane] = a1 + bj;
  if (n + 2 < n_nodes) out[(n + 2) * DFEAT + lane] = a2 + bj;
  if (n + 3 < n_nodes) out[(n + 3) * DFEAT + lane] = a3 + bj;
}

// ===========================================================================

extern "C" void kernel_launch(void* const* d_in, const int* in_sizes, int n_in,
                              void* d_out, int out_size, void* d_ws, size_t ws_size,
                              hipStream_t stream) {
  const float* feat = (const float*)d_in[0];
  const int*   src  = (const int*)d_in[1];
  const int*   dst  = (const int*)d_in[2];
  const float* W    = (const float*)d_in[3];
  const float* bias = (const float*)d_in[4];
  float* out = (float*)d_out;

  int n_nodes = in_sizes[0] / DFEAT;   // 100000
  int n_edges = in_sizes[1];           // 1600000
  int nbkt = (n_nodes + BKSZ - 1) >> SB;   // 196

  auto align_up = [](size_t x) { return (x + 255) & ~(size_t)255; };
  size_t esrc_b = align_up((size_t)n_edges * 4);
  size_t off_b  = align_up((size_t)(n_nodes + 1) * 4);
  size_t bcur_b = align_up((size_t)NBKT_PAD * 4);
  size_t ocnt_b = align_up(4);
  size_t wb_b   = align_up((size_t)DFEAT * 128 * 2);
  size_t gb_b   = align_up((size_t)(n_nodes + 1) * DFEAT * 2);  // +sentinel
  size_t need   = esrc_b + off_b + bcur_b + ocnt_b + wb_b + gb_b;

  // out must hold: main bucket regions + worst-case overflow (<= E - CAP).
  size_t ov_need = (n_edges > CAP) ? (size_t)(n_edges - CAP) * 8 : 0;
  bool pairs_fit = (size_t)out_size * 4 >= (size_t)nbkt * CAP * 4 + ov_need;
  bool ok = pairs_fit && nbkt >= 1 && nbkt <= NBKT_PAD && ws_size >= need &&
            n_nodes < (1 << 23);

  if (ok) {
    char* p = (char*)d_ws;
    int* edge_src = (int*)p;   p += esrc_b;
    int* offsets  = (int*)p;   p += off_b;
    int* bcur     = (int*)p;   p += bcur_b;
    int* ocnt     = (int*)p;   p += ocnt_b;
    unsigned short* wb = (unsigned short*)p;   p += wb_b;
    unsigned short* gb = (unsigned short*)p;
    unsigned int* pairs = (unsigned int*)d_out;   // dead before out written
    int2* ov = (int2*)((char*)d_out + (size_t)nbkt * CAP * 4);

    hipMemsetAsync(bcur, 0, bcur_b + ocnt_b, stream);   // bcur + ocnt

    int n4 = n_nodes * (DFEAT / 4);
    int nw4 = DFEAT * 128 / 4;
    int pblocks = (n_edges + PLACE_CHUNK - 1) / PLACE_CHUNK;
    gcn_place_conv<<<pblocks, 512, 0, stream>>>(
        (const float4*)feat, (ushort4*)gb, n4,
        (const float4*)W, (ushort4*)wb, nw4,
        src, dst, bcur, ocnt, pairs, ov, n_edges, nbkt);

    gcn_fillk<<<nbkt, 512, 0, stream>>>(pairs, ov, ocnt, bcur, offsets,
                                        edge_src, n_nodes, n_edges, nbkt);

    int gblocks = (n_nodes + 31) / 32;
    gcn_gather_mfma<<<gblocks, 128, 0, stream>>>(
        (const ushort4*)gb, wb, edge_src, offsets, bias, out, n_nodes);
  } else {
    size_t agg_bytes = (size_t)n_nodes * DFEAT * sizeof(float);
    float* agg = (ws_size >= agg_bytes) ? (float*)d_ws : out;
    hipMemsetAsync(agg, 0, agg_bytes, stream);
    long long st = (long long)n_edges * 16;
    gcn_scatter_kernel<<<(int)((st + 255) / 256), 256, 0, stream>>>(
        (const float4*)feat, src, dst, agg, n_edges);
    int gblocks = (n_nodes + 15) / 16;
    gcn_gemm_kernel<<<gblocks, 256, 0, stream>>>(feat, agg, W, bias, out,
                                                 n_nodes);
  }
}

// Round 15
// 94.516 us; speedup vs baseline: 1.4337x; 1.4337x over previous
//
#include <hip/hip_runtime.h>

#define DFEAT 64
#define BKSZ 512            // nodes per bucket (CSR build)
#define SB 9                // log2(BKSZ)
#define NBKT_PAD 256        // max buckets; nbkt <= 256
#define PLACE_CHUNK 4096
#define CAP 12288           // fixed slots per bucket in pairs (mean 8192)
#define FILL_CAP 12288      // LDS pair cache per bucket (48KB)

typedef __attribute__((ext_vector_type(8))) short bf16x8;
typedef __attribute__((ext_vector_type(4))) float f32x4;

__device__ inline unsigned short f2bf(float f) {
  unsigned int x = __float_as_uint(f);
  return (unsigned short)((x + 0x7fffu + ((x >> 16) & 1u)) >> 16);
}

// ===========================================================================
// K1: fused bf16 conversion (feat + sentinel row + W) AND bucket place.
// Fixed-stride bucket regions; no histogram, no global scan.  Rare overflow
// spills to ov[]; fillk merges it (free when empty).
// ===========================================================================
__global__ __launch_bounds__(512) void gcn_place_conv(
    const float4* __restrict__ feat4, ushort4* __restrict__ gb4, int n4,
    const float4* __restrict__ w4, ushort4* __restrict__ wb4, int nw4,
    const int* __restrict__ src, const int* __restrict__ dst,
    int* __restrict__ bcur, int* __restrict__ ocnt,
    unsigned int* __restrict__ pairs, int2* __restrict__ ov,
    int n_edges, int nbkt) {
  // ---- conversion (grid-stride, independent of placement) ----
  int total = n4 + 16 + nw4;
  for (int i = blockIdx.x * 512 + threadIdx.x; i < total; i += gridDim.x * 512) {
    if (i < n4) {
      float4 f = feat4[i];
      ushort4 u;
      u.x = f2bf(f.x); u.y = f2bf(f.y); u.z = f2bf(f.z); u.w = f2bf(f.w);
      gb4[i] = u;
    } else if (i < n4 + 16) {
      gb4[i] = (ushort4){0, 0, 0, 0};          // sentinel row (node n_nodes)
    } else {
      float4 f = w4[i - n4 - 16];
      ushort4 u;
      u.x = f2bf(f.x); u.y = f2bf(f.y); u.z = f2bf(f.z); u.w = f2bf(f.w);
      wb4[i - n4 - 16] = u;
    }
  }

  // ---- place ----
  __shared__ int cnt[NBKT_PAD];                    // 1 KB
  __shared__ int base[NBKT_PAD];                   // 1 KB
  __shared__ unsigned int pk[PLACE_CHUNK];         // 16 KB
  __shared__ unsigned char bk[PLACE_CHUNK];        // 4 KB
  int t = threadIdx.x;
  if (t < NBKT_PAD) cnt[t] = 0;
  __syncthreads();

  int e0 = blockIdx.x * PLACE_CHUNK;
  int e1 = min(e0 + PLACE_CHUNK, n_edges);
  for (int e = e0 + t; e < e1; e += 512) {
    int d = dst[e];
    int s = src[e];
    int b = d >> SB;
    pk[e - e0] = (unsigned)s | ((unsigned)(d & (BKSZ - 1)) << 23);
    bk[e - e0] = (unsigned char)b;
    atomicAdd(&cnt[b], 1);
  }
  __syncthreads();
  if (t < NBKT_PAD) {
    int c = cnt[t];
    base[t] = c ? atomicAdd(&bcur[t], c) : 0;   // bucket-relative reservation
    cnt[t] = 0;   // reuse as local cursor
  }
  __syncthreads();
  for (int e = e0 + t; e < e1; e += 512) {
    int b = bk[e - e0];
    int rel = base[b] + atomicAdd(&cnt[b], 1);
    unsigned p = pk[e - e0];
    if (rel < CAP) {
      pairs[b * CAP + rel] = p;
    } else {                                    // adversarial only
      int oi = atomicAdd(ocnt, 1);
      ov[oi] = make_int2((int)(p & 0x7FFFFFu), (b << 9) | (int)(p >> 23));
    }
  }
}

// ===========================================================================
// K2: per-bucket fill.  Bucket totals = min(bcur,CAP) + overflow count;
// cheap local scan -> compact CSR base; node-degree hist -> scan -> offsets
// + cursor placement of edge_src.  Overflow merged (free when empty).
// ===========================================================================
__global__ __launch_bounds__(512) void gcn_fillk(
    const unsigned int* __restrict__ pairs, const int2* __restrict__ ov,
    const int* __restrict__ ocnt_p, const int* __restrict__ bcur,
    int* __restrict__ offsets, int* __restrict__ edge_src,
    int n_nodes, int n_edges, int nbkt) {
  __shared__ int sc[2][NBKT_PAD];       // 2 KB
  __shared__ int ovb[NBKT_PAD];         // 1 KB
  __shared__ int deg[BKSZ];             // 2 KB
  __shared__ int buf[2][BKSZ];          // 4 KB
  __shared__ int cur[BKSZ];             // 2 KB
  __shared__ unsigned int lp[FILL_CAP]; // 48 KB
  int b = blockIdx.x, t = threadIdx.x;
  int onum = ocnt_p[0];

  if (t < NBKT_PAD) ovb[t] = 0;
  __syncthreads();
  for (int i = t; i < onum; i += 512) atomicAdd(&ovb[ov[i].y >> 9], 1);
  __syncthreads();

  if (t < NBKT_PAD)
    sc[0][t] = (t < nbkt) ? (min(bcur[t], CAP) + ovb[t]) : 0;
  __syncthreads();
  int pin = 0;
  for (int s = 1; s < NBKT_PAD; s <<= 1) {
    int po = pin ^ 1;
    if (t < NBKT_PAD) {
      int v = sc[pin][t];
      if (t >= s) v += sc[pin][t - s];
      sc[po][t] = v;
    }
    __syncthreads();
    pin = po;
  }
  int e0 = (b == 0) ? 0 : sc[pin][b - 1];
  int mc = min(bcur[b], CAP);
  int n0 = b << SB;
  bool fits = (mc <= FILL_CAP);

  deg[t] = 0;
  __syncthreads();
  if (fits) {
    for (int i = t; i < mc; i += 512) {
      unsigned p = pairs[b * CAP + i];
      lp[i] = p;
      atomicAdd(&deg[p >> 23], 1);
    }
  } else {
    for (int i = t; i < mc; i += 512)
      atomicAdd(&deg[pairs[b * CAP + i] >> 23], 1);
  }
  for (int i = t; i < onum; i += 512) {
    int2 o = ov[i];
    if ((o.y >> 9) == b) atomicAdd(&deg[o.y & (BKSZ - 1)], 1);
  }
  __syncthreads();
  buf[0][t] = deg[t];
  __syncthreads();
  pin = 0;
  for (int s = 1; s < BKSZ; s <<= 1) {
    int po = pin ^ 1;
    int v = buf[pin][t];
    if (t >= s) v += buf[pin][t - s];
    buf[po][t] = v;
    __syncthreads();
    pin = po;
  }
  int excl = (t == 0) ? 0 : buf[pin][t - 1];
  cur[t] = excl;
  int n = n0 + t;
  if (n < n_nodes) offsets[n] = e0 + excl;
  if (b == nbkt - 1 && t == 0) offsets[n_nodes] = n_edges;
  __syncthreads();
  if (fits) {
    for (int i = t; i < mc; i += 512) {
      unsigned p = lp[i];
      int pos = atomicAdd(&cur[p >> 23], 1);
      edge_src[e0 + pos] = (int)(p & 0x7FFFFFu);
    }
  } else {
    for (int i = t; i < mc; i += 512) {
      unsigned p = pairs[b * CAP + i];
      int pos = atomicAdd(&cur[p >> 23], 1);
      edge_src[e0 + pos] = (int)(p & 0x7FFFFFu);
    }
  }
  for (int i = t; i < onum; i += 512) {
    int2 o = ov[i];
    if ((o.y >> 9) == b) {
      int pos = atomicAdd(&cur[o.y & (BKSZ - 1)], 1);
      edge_src[e0 + pos] = o.x;
    }
  }
}

// ===========================================================================
// K3: fused gather + concat + MFMA Linear (r12/r13 verbatim -- 50.5us).
// Block = 128 thr = 2 waves; each wave owns 16 nodes, no barriers.
// ===========================================================================
__global__ __launch_bounds__(128, 8) void gcn_gather_mfma(
    const ushort4* __restrict__ gb4,         // [N+1][16] bf16, row N = zeros
    const unsigned short* __restrict__ wb,   // [64][128] bf16 W
    const int* __restrict__ edge_src,
    const int* __restrict__ offsets,
    const float* __restrict__ bias,          // [64]
    float* __restrict__ out,                 // [N][64]
    int n_nodes) {
  __shared__ unsigned short hl[2][16 * 64];   // 4 KB total (agg half only)
  int tid = threadIdx.x;
  int wave = tid >> 6, lane = tid & 63;
  int q = lane >> 4, kk = lane & 15;
  int lrow = lane & 15, lkg = lane >> 4;
  unsigned short* myhl = hl[wave];
  int node0 = blockIdx.x * 32 + wave * 16;
  const int SENT = n_nodes;

  int oidx = node0 + ((lane < 16) ? lane : 16);
  if (oidx > n_nodes) oidx = n_nodes;
  int offv = offsets[oidx];
  int nvalid = n_nodes - node0;
  if (nvalid > 16) nvalid = 16;

  int idv = SENT;
  if (nvalid > 0) {
    int o0 = __shfl(offv, 0);
    int d0 = __shfl(offv, 1) - o0;
    if (lane < d0) idv = edge_src[o0 + lane];
  }

  for (int r = 0; r < nvalid; ++r) {
    int off = __shfl(offv, r);
    int deg = __shfl(offv, r + 1) - off;

    int idnx = SENT;
    if (r + 1 < nvalid) {
      int o2 = __shfl(offv, r + 1);
      int d2 = __shfl(offv, r + 2) - o2;
      if (lane < d2) idnx = edge_src[o2 + lane];
    }

    float4 a0 = {0.f, 0.f, 0.f, 0.f}, a1 = a0, a2 = a0, a3 = a0;
    auto proc16 = [&](int idreg, int j) {
      int s0 = __shfl(idreg, j + q);
      int s1 = __shfl(idreg, j + 4 + q);
      int s2 = __shfl(idreg, j + 8 + q);
      int s3 = __shfl(idreg, j + 12 + q);
      uint2 w0 = *(const uint2*)&gb4[s0 * 16 + kk];
      uint2 w1 = *(const uint2*)&gb4[s1 * 16 + kk];
      uint2 w2 = *(const uint2*)&gb4[s2 * 16 + kk];
      uint2 w3 = *(const uint2*)&gb4[s3 * 16 + kk];
      a0.x += __uint_as_float(w0.x << 16);
      a0.y += __uint_as_float(w0.x & 0xffff0000u);
      a0.z += __uint_as_float(w0.y << 16);
      a0.w += __uint_as_float(w0.y & 0xffff0000u);
      a1.x += __uint_as_float(w1.x << 16);
      a1.y += __uint_as_float(w1.x & 0xffff0000u);
      a1.z += __uint_as_float(w1.y << 16);
      a1.w += __uint_as_float(w1.y & 0xffff0000u);
      a2.x += __uint_as_float(w2.x << 16);
      a2.y += __uint_as_float(w2.x & 0xffff0000u);
      a2.z += __uint_as_float(w2.y << 16);
      a2.w += __uint_as_float(w2.y & 0xffff0000u);
      a3.x += __uint_as_float(w3.x << 16);
      a3.y += __uint_as_float(w3.x & 0xffff0000u);
      a3.z += __uint_as_float(w3.y << 16);
      a3.w += __uint_as_float(w3.y & 0xffff0000u);
    };

    int lim = min(deg, 64);
    for (int j = 0; j < lim; j += 16) proc16(idv, j);
    for (int base = 64; base < deg; base += 64) {          // rare overflow
      int id2 = (base + lane < deg) ? edge_src[off + base + lane] : SENT;
      int lim2 = min(64, deg - base);
      for (int j = 0; j < lim2; j += 16) proc16(id2, j);
    }

    float4 acc;
    acc.x = (a0.x + a1.x) + (a2.x + a3.x);
    acc.y = (a0.y + a1.y) + (a2.y + a3.y);
    acc.z = (a0.z + a1.z) + (a2.z + a3.z);
    acc.w = (a0.w + a1.w) + (a2.w + a3.w);
    acc.x += __shfl_xor(acc.x, 16); acc.x += __shfl_xor(acc.x, 32);
    acc.y += __shfl_xor(acc.y, 16); acc.y += __shfl_xor(acc.y, 32);
    acc.z += __shfl_xor(acc.z, 16); acc.z += __shfl_xor(acc.z, 32);
    acc.w += __shfl_xor(acc.w, 16); acc.w += __shfl_xor(acc.w, 32);

    if (q == 0) {                 // agg fragment: 8B per lane, swizzled
      unsigned swz = (unsigned)((r & 7) << 4);
      char* rowp = (char*)(myhl + r * 64);
      ushort4 pk;
      pk.x = f2bf(acc.x); pk.y = f2bf(acc.y);
      pk.z = f2bf(acc.z); pk.w = f2bf(acc.w);
      *(ushort4*)(rowp + ((8u * (unsigned)kk) ^ swz)) = pk;
    }
    idv = idnx;
  }

  bf16x8 wf[4][4];
#pragma unroll
  for (int kt = 0; kt < 4; ++kt)
#pragma unroll
    for (int jt = 0; jt < 4; ++jt)
      wf[kt][jt] =
          *(const bf16x8*)(wb + (jt * 16 + lrow) * 128 + kt * 32 + lkg * 8);

  f32x4 acc[4];
#pragma unroll
  for (int jt = 0; jt < 4; ++jt) acc[jt] = (f32x4){0.f, 0.f, 0.f, 0.f};

  int nrow = node0 + lrow;
  int nload = (nrow < n_nodes) ? nrow : n_nodes;   // sentinel row if OOB
#pragma unroll
  for (int kt = 0; kt < 2; ++kt) {
    bf16x8 af = *(const bf16x8*)((const unsigned short*)gb4 +
                                 (size_t)nload * DFEAT + kt * 32 + lkg * 8);
#pragma unroll
    for (int jt = 0; jt < 4; ++jt)
      acc[jt] = __builtin_amdgcn_mfma_f32_16x16x32_bf16(af, wf[kt][jt],
                                                        acc[jt], 0, 0, 0);
  }
  unsigned aswz = (unsigned)((lrow & 7) << 4);
  const char* arow = (const char*)(myhl + lrow * 64);
#pragma unroll
  for (int kt = 2; kt < 4; ++kt) {
    bf16x8 af =
        *(const bf16x8*)(arow + ((unsigned)((kt - 2) * 64 + lkg * 16) ^ aswz));
#pragma unroll
    for (int jt = 0; jt < 4; ++jt)
      acc[jt] = __builtin_amdgcn_mfma_f32_16x16x32_bf16(af, wf[kt][jt],
                                                        acc[jt], 0, 0, 0);
  }

#pragma unroll
  for (int jt = 0; jt < 4; ++jt) {
    float bj = bias[jt * 16 + lrow];
#pragma unroll
    for (int r = 0; r < 4; ++r) {
      int n = node0 + lkg * 4 + r;
      if (n < n_nodes) out[n * DFEAT + jt * 16 + lrow] = acc[jt][r] + bj;
    }
  }
}

// ===========================================================================
// Last-resort fallback: atomic scatter + separate vector GEMM.
// ===========================================================================
__global__ __launch_bounds__(256) void gcn_scatter_kernel(
    const float4* __restrict__ feat4, const int* __restrict__ src,
    const int* __restrict__ dst, float* __restrict__ agg, int n_edges) {
  long long gid = (long long)blockIdx.x * blockDim.x + threadIdx.x;
  int e = (int)(gid >> 4);
  int c = (int)(gid & 15);
  if (e >= n_edges) return;
  float4 v = feat4[src[e] * 16 + c];
  float* p = agg + dst[e] * DFEAT + c * 4;
  atomicAdd(p + 0, v.x);
  atomicAdd(p + 1, v.y);
  atomicAdd(p + 2, v.z);
  atomicAdd(p + 3, v.w);
}

__global__ __launch_bounds__(256) void gcn_gemm_kernel(
    const float* __restrict__ feat, const float* __restrict__ agg,
    const float* __restrict__ W, const float* __restrict__ bias,
    float* __restrict__ out, int n_nodes) {
  __shared__ float4 Wl4[2048];
  __shared__ __align__(16) float hlf[16][128];
  int tid = threadIdx.x;
  for (int i = tid; i < 2048; i += 256) {
    int j = i >> 5, k4 = i & 31;
    Wl4[k4 * 64 + (j ^ (k4 & 7))] = ((const float4*)W)[i];
  }
  int node0 = blockIdx.x * 16;
  int wave = tid >> 6, lane = tid & 63;
  int mbase = wave * 4;
#pragma unroll
  for (int r = 0; r < 4; ++r) {
    int n = node0 + mbase + r;
    if (n < n_nodes) {
      hlf[mbase + r][lane]      = feat[n * DFEAT + lane];
      hlf[mbase + r][64 + lane] = agg[n * DFEAT + lane];
    }
  }
  __syncthreads();
  float a0 = 0.f, a1 = 0.f, a2 = 0.f, a3 = 0.f;
#pragma unroll 4
  for (int k4 = 0; k4 < 32; ++k4) {
    float4 w  = Wl4[k4 * 64 + (lane ^ (k4 & 7))];
    float4 h0 = *((const float4*)&hlf[mbase + 0][k4 * 4]);
    float4 h1 = *((const float4*)&hlf[mbase + 1][k4 * 4]);
    float4 h2 = *((const float4*)&hlf[mbase + 2][k4 * 4]);
    float4 h3 = *((const float4*)&hlf[mbase + 3][k4 * 4]);
    a0 += w.x * h0.x + w.y * h0.y + w.z * h0.z + w.w * h0.w;
    a1 += w.x * h1.x + w.y * h1.y + w.z * h1.z + w.w * h1.w;
    a2 += w.x * h2.x + w.y * h2.y + w.z * h2.z + w.w * h2.w;
    a3 += w.x * h3.x + w.y * h3.y + w.z * h3.z + w.w * h3.w;
  }
  float bj = bias[lane];
  int n = node0 + mbase;
  if (n + 0 < n_nodes) out[(n + 0) * DFEAT + lane] = a0 + bj;
  if (n + 1 < n_nodes) out[(n + 1) * DFEAT + lane] = a1 + bj;
  if (n + 2 < n_nodes) out[(n + 2) * DFEAT + lane] = a2 + bj;
  if (n + 3 < n_nodes) out[(n + 3) * DFEAT + lane] = a3 + bj;
}

// ===========================================================================

extern "C" void kernel_launch(void* const* d_in, const int* in_sizes, int n_in,
                              void* d_out, int out_size, void* d_ws, size_t ws_size,
                              hipStream_t stream) {
  const float* feat = (const float*)d_in[0];
  const int*   src  = (const int*)d_in[1];
  const int*   dst  = (const int*)d_in[2];
  const float* W    = (const float*)d_in[3];
  const float* bias = (const float*)d_in[4];
  float* out = (float*)d_out;

  int n_nodes = in_sizes[0] / DFEAT;   // 100000
  int n_edges = in_sizes[1];           // 1600000
  int nbkt = (n_nodes + BKSZ - 1) >> SB;   // 196

  auto align_up = [](size_t x) { return (x + 255) & ~(size_t)255; };
  size_t esrc_b = align_up((size_t)n_edges * 4);
  size_t off_b  = align_up((size_t)(n_nodes + 1) * 4);
  size_t bcur_b = align_up((size_t)NBKT_PAD * 4);
  size_t ocnt_b = align_up(4);
  size_t wb_b   = align_up((size_t)DFEAT * 128 * 2);
  size_t gb_b   = align_up((size_t)(n_nodes + 1) * DFEAT * 2);  // +sentinel
  size_t need   = esrc_b + off_b + bcur_b + ocnt_b + wb_b + gb_b;

  // out must hold: main bucket regions + worst-case overflow (<= E - CAP).
  size_t ov_need = (n_edges > CAP) ? (size_t)(n_edges - CAP) * 8 : 0;
  bool pairs_fit = (size_t)out_size * 4 >= (size_t)nbkt * CAP * 4 + ov_need;
  bool ok = pairs_fit && nbkt >= 1 && nbkt <= NBKT_PAD && ws_size >= need &&
            n_nodes < (1 << 23);

  if (ok) {
    char* p = (char*)d_ws;
    int* edge_src = (int*)p;   p += esrc_b;
    int* offsets  = (int*)p;   p += off_b;
    int* bcur     = (int*)p;   p += bcur_b;
    int* ocnt     = (int*)p;   p += ocnt_b;
    unsigned short* wb = (unsigned short*)p;   p += wb_b;
    unsigned short* gb = (unsigned short*)p;
    unsigned int* pairs = (unsigned int*)d_out;   // dead before out written
    int2* ov = (int2*)((char*)d_out + (size_t)nbkt * CAP * 4);

    hipMemsetAsync(bcur, 0, bcur_b + ocnt_b, stream);   // bcur + ocnt

    int n4 = n_nodes * (DFEAT / 4);
    int nw4 = DFEAT * 128 / 4;
    int pblocks = (n_edges + PLACE_CHUNK - 1) / PLACE_CHUNK;
    gcn_place_conv<<<pblocks, 512, 0, stream>>>(
        (const float4*)feat, (ushort4*)gb, n4,
        (const float4*)W, (ushort4*)wb, nw4,
        src, dst, bcur, ocnt, pairs, ov, n_edges, nbkt);

    gcn_fillk<<<nbkt, 512, 0, stream>>>(pairs, ov, ocnt, bcur, offsets,
                                        edge_src, n_nodes, n_edges, nbkt);

    int gblocks = (n_nodes + 31) / 32;
    gcn_gather_mfma<<<gblocks, 128, 0, stream>>>(
        (const ushort4*)gb, wb, edge_src, offsets, bias, out, n_nodes);
  } else {
    size_t agg_bytes = (size_t)n_nodes * DFEAT * sizeof(float);
    float* agg = (ws_size >= agg_bytes) ? (float*)d_ws : out;
    hipMemsetAsync(agg, 0, agg_bytes, stream);
    long long st = (long long)n_edges * 16;
    gcn_scatter_kernel<<<(int)((st + 255) / 256), 256, 0, stream>>>(
        (const float4*)feat, src, dst, agg, n_edges);
    int gblocks = (n_nodes + 15) / 16;
    gcn_gemm_kernel<<<gblocks, 256, 0, stream>>>(feat, agg, W, bias, out,
                                                 n_nodes);
  }
}